// Round 5
// baseline (296.882 us; speedup 1.0000x reference)
//
#include <hip/hip_runtime.h>
#include <hip/hip_bf16.h>

#define N_NODES 50000
#define E_EDGES 500000
#define HID 128
#define NHEAD 4
#define HDIM 32
#define SCAN_BLOCKS ((N_NODES + 255) / 256)   // 196

// ---------------------------------------------------------------------------
// FiLM: film[j] = task @ W_film[:,j] + b_film[j]; store gamma-factor and beta
// ---------------------------------------------------------------------------
__global__ __launch_bounds__(256) void film_kernel(
    const float* __restrict__ task, const float* __restrict__ Wf,
    const float* __restrict__ bf, float* __restrict__ film)
{
    __shared__ float tsk[HID];
    const int t = threadIdx.x;
    if (t < HID) tsk[t] = task[t];
    __syncthreads();
    float acc = bf[t];
    #pragma unroll 8
    for (int k = 0; k < HID; ++k)
        acc = fmaf(tsk[k], Wf[k * 256 + t], acc);
    if (t < HID) film[t] = 1.f + 0.5f * tanhf(acc);   // gamma factor
    else         film[t] = acc;                        // beta
}

// ---------------------------------------------------------------------------
// Fused x_src / x_dst GEMM, 64-node tile, 16 nodes/thread.
// waves 0-1 -> W_src half, waves 2-3 -> W_dst half.
// lane&31 -> column group (4 cols); lane>>5 -> 16-node subset.
// Paired lanes (l, l+32) read identical W addresses -> broadcast.
// ---------------------------------------------------------------------------
__global__ __launch_bounds__(256) void gemm_srcdst(
    const float* __restrict__ A,
    const float* __restrict__ Ws, const float* __restrict__ bs,
    const float* __restrict__ Wd, const float* __restrict__ bd,
    float* __restrict__ xs, float* __restrict__ xd)
{
    __shared__ float a_tile[64][HID];
    const int t  = threadIdx.x;
    const int nb = blockIdx.x * 64;

    #pragma unroll
    for (int i = 0; i < 8; ++i) {
        int f  = t + 256 * i;        // float4 index within tile
        int m  = f >> 5;             // node within tile (32 float4 per row)
        int k4 = f & 31;
        int node = nb + m;
        float4 v;
        if (node < N_NODES) v = *(const float4*)(A + (size_t)node * HID + k4 * 4);
        else { v.x = v.y = v.z = v.w = 0.f; }
        *(float4*)&a_tile[m][k4 * 4] = v;
    }
    __syncthreads();

    const int wave = t >> 6;
    const int lane = t & 63;
    const bool is_src = (wave < 2);
    const int cc = (lane & 31) * 4;
    const int m0 = (wave & 1) * 32 + (lane >> 5) * 16;
    const float* W    = is_src ? Ws : Wd;
    const float* bias = is_src ? bs : bd;
    float*       xout = is_src ? xs : xd;

    float acc[16][4];
    #pragma unroll
    for (int m = 0; m < 16; ++m)
        #pragma unroll
        for (int j = 0; j < 4; ++j) acc[m][j] = 0.f;

    for (int kc = 0; kc < 32; ++kc) {
        const int k0 = kc * 4;
        const float4 w0 = *(const float4*)(W + (size_t)(k0 + 0) * HID + cc);
        const float4 w1 = *(const float4*)(W + (size_t)(k0 + 1) * HID + cc);
        const float4 w2 = *(const float4*)(W + (size_t)(k0 + 2) * HID + cc);
        const float4 w3 = *(const float4*)(W + (size_t)(k0 + 3) * HID + cc);
        #pragma unroll
        for (int m = 0; m < 16; ++m) {
            const float4 av = *(const float4*)&a_tile[m0 + m][k0];
            acc[m][0] = fmaf(av.x, w0.x, acc[m][0]);
            acc[m][1] = fmaf(av.x, w0.y, acc[m][1]);
            acc[m][2] = fmaf(av.x, w0.z, acc[m][2]);
            acc[m][3] = fmaf(av.x, w0.w, acc[m][3]);
            acc[m][0] = fmaf(av.y, w1.x, acc[m][0]);
            acc[m][1] = fmaf(av.y, w1.y, acc[m][1]);
            acc[m][2] = fmaf(av.y, w1.z, acc[m][2]);
            acc[m][3] = fmaf(av.y, w1.w, acc[m][3]);
            acc[m][0] = fmaf(av.z, w2.x, acc[m][0]);
            acc[m][1] = fmaf(av.z, w2.y, acc[m][1]);
            acc[m][2] = fmaf(av.z, w2.z, acc[m][2]);
            acc[m][3] = fmaf(av.z, w2.w, acc[m][3]);
            acc[m][0] = fmaf(av.w, w3.x, acc[m][0]);
            acc[m][1] = fmaf(av.w, w3.y, acc[m][1]);
            acc[m][2] = fmaf(av.w, w3.z, acc[m][2]);
            acc[m][3] = fmaf(av.w, w3.w, acc[m][3]);
        }
    }

    const float4 bv = *(const float4*)(bias + cc);
    #pragma unroll
    for (int m = 0; m < 16; ++m) {
        const int node = nb + m0 + m;
        if (node < N_NODES) {
            float4 o;
            o.x = acc[m][0] + bv.x;
            o.y = acc[m][1] + bv.y;
            o.z = acc[m][2] + bv.z;
            o.w = acc[m][3] + bv.w;
            *(float4*)(xout + (size_t)node * HID + cc) = o;
        }
    }
}

// ---------------------------------------------------------------------------
// CSR build, step 1: in-degree histogram over dst
// ---------------------------------------------------------------------------
__global__ __launch_bounds__(256) void hist_kernel(
    const int* __restrict__ ei, int* __restrict__ deg)
{
    const int e = blockIdx.x * 256 + threadIdx.x;
    if (e < E_EDGES) atomicAdd(&deg[ei[E_EDGES + e]], 1);
}

// ---------------------------------------------------------------------------
// Two-level scan, step A: per-block (256-wide) reduction of deg
// ---------------------------------------------------------------------------
__global__ __launch_bounds__(256) void reduce_blocks(
    const int* __restrict__ deg, int* __restrict__ blocksum)
{
    __shared__ int ws_[4];
    const int t = threadIdx.x;
    const int i = blockIdx.x * 256 + t;
    int v = (i < N_NODES) ? deg[i] : 0;
    #pragma unroll
    for (int off = 32; off; off >>= 1) v += __shfl_down(v, off);
    if ((t & 63) == 0) ws_[t >> 6] = v;
    __syncthreads();
    if (t == 0) blocksum[blockIdx.x] = ws_[0] + ws_[1] + ws_[2] + ws_[3];
}

// ---------------------------------------------------------------------------
// Two-level scan, step B: single small block scans the 196 block sums
// -> exclusive block offsets
// ---------------------------------------------------------------------------
__global__ __launch_bounds__(256) void scan_blocksums(
    const int* __restrict__ blocksum, int* __restrict__ blockoff,
    int* __restrict__ rowptr)
{
    __shared__ int wtot[4];
    const int t    = threadIdx.x;
    const int lane = t & 63;
    const int w    = t >> 6;
    int v = (t < SCAN_BLOCKS) ? blocksum[t] : 0;
    const int own = v;
    #pragma unroll
    for (int off = 1; off < 64; off <<= 1) {
        const int u = __shfl_up(v, off);
        if (lane >= off) v += u;
    }
    if (lane == 63) wtot[w] = v;
    __syncthreads();
    int woff = 0;
    #pragma unroll
    for (int k = 0; k < 4; ++k) if (k < w) woff += wtot[k];
    if (t < SCAN_BLOCKS) blockoff[t] = woff + v - own;   // exclusive
    if (t == 0) rowptr[N_NODES] = E_EDGES;
}

// ---------------------------------------------------------------------------
// Two-level scan, step C: per-block exclusive scan + block offset
// -> rowptr, cursor
// ---------------------------------------------------------------------------
__global__ __launch_bounds__(256) void scan_within(
    const int* __restrict__ deg, const int* __restrict__ blockoff,
    int* __restrict__ rowptr, int* __restrict__ cursor)
{
    __shared__ int wtot[4];
    const int t    = threadIdx.x;
    const int lane = t & 63;
    const int w    = t >> 6;
    const int i    = blockIdx.x * 256 + t;
    int v = (i < N_NODES) ? deg[i] : 0;
    const int own = v;
    #pragma unroll
    for (int off = 1; off < 64; off <<= 1) {
        const int u = __shfl_up(v, off);
        if (lane >= off) v += u;
    }
    if (lane == 63) wtot[w] = v;
    __syncthreads();
    int woff = blockoff[blockIdx.x];
    #pragma unroll
    for (int k = 0; k < 4; ++k) if (k < w) woff += wtot[k];
    if (i < N_NODES) {
        const int ex = woff + v - own;
        rowptr[i] = ex;
        cursor[i] = ex;
    }
}

// ---------------------------------------------------------------------------
// CSR build, step 3: scatter packed (src | etype<<16) records into dst bins
// ---------------------------------------------------------------------------
__global__ __launch_bounds__(256) void scatter_kernel(
    const int* __restrict__ ei, const int* __restrict__ et,
    int* __restrict__ cursor, int* __restrict__ pack)
{
    const int e = blockIdx.x * 256 + threadIdx.x;
    if (e < E_EDGES) {
        const int d = ei[E_EDGES + e];
        const int pos = atomicAdd(&cursor[d], 1);
        pack[pos] = ei[e] | (et[e] << 16);    // src < 65536, etype < 8
    }
}

// ---------------------------------------------------------------------------
// Gather-aggregate: one 32-lane group per dst node. Walks in-edges, computes
// ex = exp(logit), accumulates ex*x_src and ex in registers; normalizes and
// writes one 512B row per node. Zero atomics.
// ---------------------------------------------------------------------------
__global__ __launch_bounds__(256) void gather_agg(
    const int* __restrict__ rowptr, const int* __restrict__ pack,
    const float* __restrict__ xsrc, const float* __restrict__ xdst,
    const float* __restrict__ eemb, const float* __restrict__ att,
    float* __restrict__ agg)
{
    const int lane = threadIdx.x & 31;
    const int grp  = threadIdx.x >> 5;
    const int node = blockIdx.x * 8 + grp;
    if (node >= N_NODES) return;

    const float4 av = *(const float4*)(att + lane * 4);
    const float4 xd = *(const float4*)(xdst + (size_t)node * HID + lane * 4);

    float a0 = 0.f, a1 = 0.f, a2 = 0.f, a3 = 0.f, sum = 0.f;
    const int b = rowptr[node];
    const int e = rowptr[node + 1];

    int i = b;
    for (; i + 1 < e; i += 2) {               // 2-wide for load overlap
        const int pk0 = pack[i];
        const int pk1 = pack[i + 1];
        const int s0 = pk0 & 0xFFFF, ty0 = pk0 >> 16;
        const int s1 = pk1 & 0xFFFF, ty1 = pk1 >> 16;
        const float4 xs0 = *(const float4*)(xsrc + (size_t)s0 * HID + lane * 4);
        const float4 ev0 = *(const float4*)(eemb + (size_t)ty0 * HID + lane * 4);
        const float4 xs1 = *(const float4*)(xsrc + (size_t)s1 * HID + lane * 4);
        const float4 ev1 = *(const float4*)(eemb + (size_t)ty1 * HID + lane * 4);
        float c, p0 = 0.f, p1 = 0.f;
        c = xs0.x + xd.x + ev0.x; c = (c > 0.f) ? c : 0.2f * c; p0 = fmaf(c, av.x, p0);
        c = xs0.y + xd.y + ev0.y; c = (c > 0.f) ? c : 0.2f * c; p0 = fmaf(c, av.y, p0);
        c = xs0.z + xd.z + ev0.z; c = (c > 0.f) ? c : 0.2f * c; p0 = fmaf(c, av.z, p0);
        c = xs0.w + xd.w + ev0.w; c = (c > 0.f) ? c : 0.2f * c; p0 = fmaf(c, av.w, p0);
        c = xs1.x + xd.x + ev1.x; c = (c > 0.f) ? c : 0.2f * c; p1 = fmaf(c, av.x, p1);
        c = xs1.y + xd.y + ev1.y; c = (c > 0.f) ? c : 0.2f * c; p1 = fmaf(c, av.y, p1);
        c = xs1.z + xd.z + ev1.z; c = (c > 0.f) ? c : 0.2f * c; p1 = fmaf(c, av.z, p1);
        c = xs1.w + xd.w + ev1.w; c = (c > 0.f) ? c : 0.2f * c; p1 = fmaf(c, av.w, p1);
        p0 += __shfl_xor(p0, 1); p1 += __shfl_xor(p1, 1);
        p0 += __shfl_xor(p0, 2); p1 += __shfl_xor(p1, 2);
        p0 += __shfl_xor(p0, 4); p1 += __shfl_xor(p1, 4);
        const float ex0 = expf(p0);
        const float ex1 = expf(p1);
        a0 = fmaf(ex0, xs0.x, a0); a1 = fmaf(ex0, xs0.y, a1);
        a2 = fmaf(ex0, xs0.z, a2); a3 = fmaf(ex0, xs0.w, a3);
        a0 = fmaf(ex1, xs1.x, a0); a1 = fmaf(ex1, xs1.y, a1);
        a2 = fmaf(ex1, xs1.z, a2); a3 = fmaf(ex1, xs1.w, a3);
        sum += ex0 + ex1;
    }
    if (i < e) {                              // tail
        const int pk0 = pack[i];
        const int s0 = pk0 & 0xFFFF, ty0 = pk0 >> 16;
        const float4 xs0 = *(const float4*)(xsrc + (size_t)s0 * HID + lane * 4);
        const float4 ev0 = *(const float4*)(eemb + (size_t)ty0 * HID + lane * 4);
        float c, p0 = 0.f;
        c = xs0.x + xd.x + ev0.x; c = (c > 0.f) ? c : 0.2f * c; p0 = fmaf(c, av.x, p0);
        c = xs0.y + xd.y + ev0.y; c = (c > 0.f) ? c : 0.2f * c; p0 = fmaf(c, av.y, p0);
        c = xs0.z + xd.z + ev0.z; c = (c > 0.f) ? c : 0.2f * c; p0 = fmaf(c, av.z, p0);
        c = xs0.w + xd.w + ev0.w; c = (c > 0.f) ? c : 0.2f * c; p0 = fmaf(c, av.w, p0);
        p0 += __shfl_xor(p0, 1);
        p0 += __shfl_xor(p0, 2);
        p0 += __shfl_xor(p0, 4);
        const float ex0 = expf(p0);
        a0 = fmaf(ex0, xs0.x, a0); a1 = fmaf(ex0, xs0.y, a1);
        a2 = fmaf(ex0, xs0.z, a2); a3 = fmaf(ex0, xs0.w, a3);
        sum += ex0;
    }

    const float inv = 1.f / fmaxf(sum, 1e-12f);
    float4 o;
    o.x = a0 * inv; o.y = a1 * inv; o.z = a2 * inv; o.w = a3 * inv;
    *(float4*)(agg + (size_t)node * HID + lane * 4) = o;
}

// ---------------------------------------------------------------------------
// Finalize (GEMM-structured): 64-node tile in LDS, 256 threads.
// Single barrier after staging; LN via 32-lane shuffles — no LDS round-trip.
// ---------------------------------------------------------------------------
__global__ __launch_bounds__(256) void finalize(
    const float* __restrict__ agg,
    const float* __restrict__ A,   const float* __restrict__ Wo,
    const float* __restrict__ bo,  const float* __restrict__ film,
    const float* __restrict__ nw_, const float* __restrict__ nb_,
    float* __restrict__ out)
{
    __shared__ float a_tile[64][HID];
    const int t  = threadIdx.x;
    const int nb = blockIdx.x * 64;

    #pragma unroll
    for (int i = 0; i < 8; ++i) {
        int f  = t + 256 * i;        // float4 index within tile
        int m  = f >> 5;
        int k4 = f & 31;
        int node = nb + m;
        float4 v;
        if (node < N_NODES) v = *(const float4*)(agg + (size_t)node * HID + k4 * 4);
        else { v.x = v.y = v.z = v.w = 0.f; }
        *(float4*)&a_tile[m][k4 * 4] = v;
    }
    __syncthreads();

    const int cg = t & 31;
    const int rg = t >> 5;            // 8 row-groups of 8 nodes
    const int cc = cg * 4;
    const int m0 = rg * 8;

    float acc[8][4];
    #pragma unroll
    for (int m = 0; m < 8; ++m)
        #pragma unroll
        for (int j = 0; j < 4; ++j) acc[m][j] = 0.f;

    for (int kc = 0; kc < 32; ++kc) {
        const int k0 = kc * 4;
        const float4 w0 = *(const float4*)(Wo + (size_t)(k0 + 0) * HID + cc);
        const float4 w1 = *(const float4*)(Wo + (size_t)(k0 + 1) * HID + cc);
        const float4 w2 = *(const float4*)(Wo + (size_t)(k0 + 2) * HID + cc);
        const float4 w3 = *(const float4*)(Wo + (size_t)(k0 + 3) * HID + cc);
        #pragma unroll
        for (int m = 0; m < 8; ++m) {
            const float4 av = *(const float4*)&a_tile[m0 + m][k0];
            acc[m][0] = fmaf(av.x, w0.x, acc[m][0]);
            acc[m][1] = fmaf(av.x, w0.y, acc[m][1]);
            acc[m][2] = fmaf(av.x, w0.z, acc[m][2]);
            acc[m][3] = fmaf(av.x, w0.w, acc[m][3]);
            acc[m][0] = fmaf(av.y, w1.x, acc[m][0]);
            acc[m][1] = fmaf(av.y, w1.y, acc[m][1]);
            acc[m][2] = fmaf(av.y, w1.z, acc[m][2]);
            acc[m][3] = fmaf(av.y, w1.w, acc[m][3]);
            acc[m][0] = fmaf(av.z, w2.x, acc[m][0]);
            acc[m][1] = fmaf(av.z, w2.y, acc[m][1]);
            acc[m][2] = fmaf(av.z, w2.z, acc[m][2]);
            acc[m][3] = fmaf(av.z, w2.w, acc[m][3]);
            acc[m][0] = fmaf(av.w, w3.x, acc[m][0]);
            acc[m][1] = fmaf(av.w, w3.y, acc[m][1]);
            acc[m][2] = fmaf(av.w, w3.z, acc[m][2]);
            acc[m][3] = fmaf(av.w, w3.w, acc[m][3]);
        }
    }

    const float4 bv  = *(const float4*)(bo   + cc);
    const float4 gfv = *(const float4*)(film + cc);
    const float4 btv = *(const float4*)(film + HID + cc);
    const float4 nwv = *(const float4*)(nw_  + cc);
    const float4 nbv = *(const float4*)(nb_  + cc);

    #pragma unroll
    for (int m = 0; m < 8; ++m) {
        const int node = nb + m0 + m;
        float4 y;
        float4 r;
        if (node < N_NODES) r = *(const float4*)(A + (size_t)node * HID + cc);
        else { r.x = r.y = r.z = r.w = 0.f; }
        y.x = fmaf(acc[m][0] + bv.x, gfv.x, btv.x) + r.x;
        y.y = fmaf(acc[m][1] + bv.y, gfv.y, btv.y) + r.y;
        y.z = fmaf(acc[m][2] + bv.z, gfv.z, btv.z) + r.z;
        y.w = fmaf(acc[m][3] + bv.w, gfv.w, btv.w) + r.w;

        float s1 = y.x + y.y + y.z + y.w;
        float s2 = y.x * y.x + y.y * y.y + y.z * y.z + y.w * y.w;
        #pragma unroll
        for (int off = 1; off < 32; off <<= 1) {
            s1 += __shfl_xor(s1, off);
            s2 += __shfl_xor(s2, off);
        }
        const float mu   = s1 * (1.f / 128.f);
        const float var  = s2 * (1.f / 128.f) - mu * mu;
        const float rsig = rsqrtf(var + 1e-5f);
        if (node < N_NODES) {
            float4 o;
            o.x = (y.x - mu) * rsig * nwv.x + nbv.x;
            o.y = (y.y - mu) * rsig * nwv.y + nbv.y;
            o.z = (y.z - mu) * rsig * nwv.z + nbv.z;
            o.w = (y.w - mu) * rsig * nwv.w + nbv.w;
            *(float4*)(out + (size_t)node * HID + cc) = o;
        }
    }
}

// ---------------------------------------------------------------------------
extern "C" void kernel_launch(void* const* d_in, const int* in_sizes, int n_in,
                              void* d_out, int out_size, void* d_ws, size_t ws_size,
                              hipStream_t stream)
{
    const float* node_emb = (const float*)d_in[0];
    const int*   edge_idx = (const int*)  d_in[1];
    const int*   edge_ty  = (const int*)  d_in[2];
    const float* task     = (const float*)d_in[3];
    const float* W_src    = (const float*)d_in[4];
    const float* b_src    = (const float*)d_in[5];
    const float* W_dst    = (const float*)d_in[6];
    const float* b_dst    = (const float*)d_in[7];
    const float* edge_emb = (const float*)d_in[8];
    const float* att      = (const float*)d_in[9];
    const float* W_out    = (const float*)d_in[10];
    const float* b_out    = (const float*)d_in[11];
    const float* norm_w   = (const float*)d_in[12];
    const float* norm_b   = (const float*)d_in[13];
    const float* W_film   = (const float*)d_in[14];
    const float* b_film   = (const float*)d_in[15];
    float* out = (float*)d_out;

    char* ws = (char*)d_ws;
    float* x_src    = (float*)ws;                            ws += (size_t)N_NODES * HID * 4;
    float* x_dst    = (float*)ws;                            ws += (size_t)N_NODES * HID * 4;
    float* agg      = (float*)ws;                            ws += (size_t)N_NODES * HID * 4;
    float* film     = (float*)ws;                            ws += 256 * 4;
    int*   deg      = (int*)ws;                              ws += (size_t)N_NODES * 4;
    int*   rowptr   = (int*)ws;                              ws += (size_t)(N_NODES + 1) * 4;
    int*   cursor   = (int*)ws;                              ws += (size_t)N_NODES * 4;
    int*   blocksum = (int*)ws;                              ws += 256 * 4;
    int*   blockoff = (int*)ws;                              ws += 256 * 4;
    int*   pack     = (int*)ws;                              ws += (size_t)E_EDGES * 4;

    hipMemsetAsync(deg, 0, (size_t)N_NODES * sizeof(int), stream);

    film_kernel<<<1, 256, 0, stream>>>(task, W_film, b_film, film);
    hist_kernel<<<(E_EDGES + 255) / 256, 256, 0, stream>>>(edge_idx, deg);
    gemm_srcdst<<<(N_NODES + 63) / 64, 256, 0, stream>>>(
        node_emb, W_src, b_src, W_dst, b_dst, x_src, x_dst);
    reduce_blocks<<<SCAN_BLOCKS, 256, 0, stream>>>(deg, blocksum);
    scan_blocksums<<<1, 256, 0, stream>>>(blocksum, blockoff, rowptr);
    scan_within<<<SCAN_BLOCKS, 256, 0, stream>>>(deg, blockoff, rowptr, cursor);
    scatter_kernel<<<(E_EDGES + 255) / 256, 256, 0, stream>>>(
        edge_idx, edge_ty, cursor, pack);
    gather_agg<<<(N_NODES + 7) / 8, 256, 0, stream>>>(
        rowptr, pack, x_src, x_dst, edge_emb, att, agg);
    finalize<<<(N_NODES + 63) / 64, 256, 0, stream>>>(
        agg, node_emb, W_out, b_out, film, norm_w, norm_b, out);
}

// Round 6
// 290.038 us; speedup vs baseline: 1.0236x; 1.0236x over previous
//
#include <hip/hip_runtime.h>
#include <hip/hip_bf16.h>

#define N_NODES 50000
#define E_EDGES 500000
#define HID 128
#define NHEAD 4
#define HDIM 32
#define SCAN_BLOCKS ((N_NODES + 255) / 256)   // 196

typedef __attribute__((ext_vector_type(8))) short bf16x8;   // 8 bf16 = 4 VGPR
typedef __attribute__((ext_vector_type(4))) float f32x4;

static __device__ __forceinline__ float b2f(unsigned short u) {
    return __uint_as_float((unsigned int)u << 16);
}
static __device__ __forceinline__ unsigned short f2b(float f) {
    unsigned int u = __float_as_uint(f);
    u += 0x7FFFu + ((u >> 16) & 1u);          // round-to-nearest-even
    return (unsigned short)(u >> 16);
}

// ---------------------------------------------------------------------------
// FiLM: film[j] = task @ W_film[:,j] + b_film[j]; store gamma-factor and beta
// ---------------------------------------------------------------------------
__global__ __launch_bounds__(256) void film_kernel(
    const float* __restrict__ task, const float* __restrict__ Wf,
    const float* __restrict__ bf, float* __restrict__ film)
{
    __shared__ float tsk[HID];
    const int t = threadIdx.x;
    if (t < HID) tsk[t] = task[t];
    __syncthreads();
    float acc = bf[t];
    #pragma unroll 8
    for (int k = 0; k < HID; ++k)
        acc = fmaf(tsk[k], Wf[k * 256 + t], acc);
    if (t < HID) film[t] = 1.f + 0.5f * tanhf(acc);   // gamma factor
    else         film[t] = acc;                        // beta
}

// ---------------------------------------------------------------------------
// Weight prep: B1[n][k] = bf16( n<128 ? W_src[k][n] : W_dst[k][n-128] )
// (transposed so MFMA B-fragments are contiguous 16B slices)
// ---------------------------------------------------------------------------
__global__ __launch_bounds__(256) void prep_weights(
    const float* __restrict__ Ws, const float* __restrict__ Wd,
    short* __restrict__ B1)
{
    const int id = blockIdx.x * 256 + threadIdx.x;   // 256*128 total
    const int n = id >> 7;
    const int k = id & 127;
    const float v = (n < HID) ? Ws[(size_t)k * HID + n]
                              : Wd[(size_t)k * HID + (n - HID)];
    B1[(size_t)n * HID + k] = (short)f2b(v);
}

// ---------------------------------------------------------------------------
// MFMA input GEMM: x_{src,dst} = node_emb @ [W_src | W_dst] + bias, in bf16.
// 64-node tile, 4 waves; wave w owns rows w*16..+15 (one M-frag), all 256
// cols (16 N-frags), K=128 in 4 k-steps of 32.
// A staged fp32->bf16 in LDS with XOR swizzle (G4: kill stride-256B conflict).
// B-frags read straight from L2 (bf16 B^T rows are contiguous 16B slices).
// C/D layout (m89-verified): col = lane&15, row = (lane>>4)*4 + reg.
// ---------------------------------------------------------------------------
__global__ __launch_bounds__(256) void gemm_mfma(
    const float* __restrict__ A, const short* __restrict__ B1,
    const float* __restrict__ bs, const float* __restrict__ bd,
    unsigned short* __restrict__ xs, unsigned short* __restrict__ xd)
{
    __shared__ unsigned short a_lds[64 * HID];    // 16 KB, bf16, swizzled
    const int t  = threadIdx.x;
    const int nb = blockIdx.x * 64;

    // stage: 64 rows x 32 float4 = 2048 float4, 8 per thread
    #pragma unroll
    for (int i = 0; i < 8; ++i) {
        const int f   = t + 256 * i;
        const int row = f >> 5;
        const int k4  = f & 31;
        const int node = nb + row;
        float4 v;
        if (node < N_NODES) v = *(const float4*)(A + (size_t)node * HID + k4 * 4);
        else { v.x = v.y = v.z = v.w = 0.f; }
        ushort4 h;
        h.x = f2b(v.x); h.y = f2b(v.y); h.z = f2b(v.z); h.w = f2b(v.w);
        int byte = row * 256 + k4 * 8;
        byte ^= (row & 7) << 4;                   // XOR swizzle, 16B granules
        *(ushort4*)((char*)a_lds + byte) = h;
    }
    __syncthreads();

    const int w   = t >> 6;
    const int l   = t & 63;
    const int l15 = l & 15;
    const int kg  = l >> 4;                       // 0..3 k-group
    const int r   = w * 16 + l15;                 // A row within tile

    f32x4 acc[16];
    #pragma unroll
    for (int nf = 0; nf < 16; ++nf) acc[nf] = (f32x4){0.f, 0.f, 0.f, 0.f};

    #pragma unroll
    for (int ks = 0; ks < 4; ++ks) {
        int abyte = r * 256 + ks * 64 + kg * 16;
        abyte ^= (r & 7) << 4;
        const bf16x8 a = *(const bf16x8*)((char*)a_lds + abyte);
        #pragma unroll
        for (int nf = 0; nf < 16; ++nf) {
            const bf16x8 b = *(const bf16x8*)(
                B1 + (size_t)(nf * 16 + l15) * HID + ks * 32 + kg * 8);
            acc[nf] = __builtin_amdgcn_mfma_f32_16x16x32_bf16(a, b, acc[nf], 0, 0, 0);
        }
    }

    // epilogue: bias, bf16 store. node = nb + w*16 + kg*4 + j, col = nf*16+l15
    #pragma unroll
    for (int nf = 0; nf < 16; ++nf) {
        const int col = nf * 16 + l15;
        const bool is_src = (col < HID);
        const float bias = is_src ? bs[col] : bd[col - HID];
        #pragma unroll
        for (int j = 0; j < 4; ++j) {
            const int node = nb + w * 16 + kg * 4 + j;
            if (node < N_NODES) {
                const unsigned short us = f2b(acc[nf][j] + bias);
                if (is_src) xs[(size_t)node * HID + col] = us;
                else        xd[(size_t)node * HID + (col - HID)] = us;
            }
        }
    }
}

// ---------------------------------------------------------------------------
// CSR build, step 1: in-degree histogram over dst
// ---------------------------------------------------------------------------
__global__ __launch_bounds__(256) void hist_kernel(
    const int* __restrict__ ei, int* __restrict__ deg)
{
    const int e = blockIdx.x * 256 + threadIdx.x;
    if (e < E_EDGES) atomicAdd(&deg[ei[E_EDGES + e]], 1);
}

// ---------------------------------------------------------------------------
// Two-level scan, step A: per-block (256-wide) reduction of deg
// ---------------------------------------------------------------------------
__global__ __launch_bounds__(256) void reduce_blocks(
    const int* __restrict__ deg, int* __restrict__ blocksum)
{
    __shared__ int ws_[4];
    const int t = threadIdx.x;
    const int i = blockIdx.x * 256 + t;
    int v = (i < N_NODES) ? deg[i] : 0;
    #pragma unroll
    for (int off = 32; off; off >>= 1) v += __shfl_down(v, off);
    if ((t & 63) == 0) ws_[t >> 6] = v;
    __syncthreads();
    if (t == 0) blocksum[blockIdx.x] = ws_[0] + ws_[1] + ws_[2] + ws_[3];
}

// ---------------------------------------------------------------------------
// Two-level scan, step B: scan the 196 block sums -> exclusive block offsets
// ---------------------------------------------------------------------------
__global__ __launch_bounds__(256) void scan_blocksums(
    const int* __restrict__ blocksum, int* __restrict__ blockoff,
    int* __restrict__ rowptr)
{
    __shared__ int wtot[4];
    const int t    = threadIdx.x;
    const int lane = t & 63;
    const int w    = t >> 6;
    int v = (t < SCAN_BLOCKS) ? blocksum[t] : 0;
    const int own = v;
    #pragma unroll
    for (int off = 1; off < 64; off <<= 1) {
        const int u = __shfl_up(v, off);
        if (lane >= off) v += u;
    }
    if (lane == 63) wtot[w] = v;
    __syncthreads();
    int woff = 0;
    #pragma unroll
    for (int k = 0; k < 4; ++k) if (k < w) woff += wtot[k];
    if (t < SCAN_BLOCKS) blockoff[t] = woff + v - own;   // exclusive
    if (t == 0) rowptr[N_NODES] = E_EDGES;
}

// ---------------------------------------------------------------------------
// Two-level scan, step C: per-block exclusive scan + offset -> rowptr, cursor
// ---------------------------------------------------------------------------
__global__ __launch_bounds__(256) void scan_within(
    const int* __restrict__ deg, const int* __restrict__ blockoff,
    int* __restrict__ rowptr, int* __restrict__ cursor)
{
    __shared__ int wtot[4];
    const int t    = threadIdx.x;
    const int lane = t & 63;
    const int w    = t >> 6;
    const int i    = blockIdx.x * 256 + t;
    int v = (i < N_NODES) ? deg[i] : 0;
    const int own = v;
    #pragma unroll
    for (int off = 1; off < 64; off <<= 1) {
        const int u = __shfl_up(v, off);
        if (lane >= off) v += u;
    }
    if (lane == 63) wtot[w] = v;
    __syncthreads();
    int woff = blockoff[blockIdx.x];
    #pragma unroll
    for (int k = 0; k < 4; ++k) if (k < w) woff += wtot[k];
    if (i < N_NODES) {
        const int ex = woff + v - own;
        rowptr[i] = ex;
        cursor[i] = ex;
    }
}

// ---------------------------------------------------------------------------
// CSR build, step 3: scatter packed (src | etype<<16) records into dst bins
// ---------------------------------------------------------------------------
__global__ __launch_bounds__(256) void scatter_kernel(
    const int* __restrict__ ei, const int* __restrict__ et,
    int* __restrict__ cursor, int* __restrict__ pack)
{
    const int e = blockIdx.x * 256 + threadIdx.x;
    if (e < E_EDGES) {
        const int d = ei[E_EDGES + e];
        const int pos = atomicAdd(&cursor[d], 1);
        pack[pos] = ei[e] | (et[e] << 16);    // src < 65536, etype < 8
    }
}

// ---------------------------------------------------------------------------
// Gather-aggregate (bf16 x inputs): one 32-lane group per dst node.
// ---------------------------------------------------------------------------
__global__ __launch_bounds__(256) void gather_agg(
    const int* __restrict__ rowptr, const int* __restrict__ pack,
    const unsigned short* __restrict__ xsrc,
    const unsigned short* __restrict__ xdst,
    const float* __restrict__ eemb, const float* __restrict__ att,
    float* __restrict__ agg)
{
    const int lane = threadIdx.x & 31;
    const int grp  = threadIdx.x >> 5;
    const int node = blockIdx.x * 8 + grp;
    if (node >= N_NODES) return;

    const float4 av = *(const float4*)(att + lane * 4);
    const ushort4 xdu = *(const ushort4*)(xdst + (size_t)node * HID + lane * 4);
    const float xdx = b2f(xdu.x), xdy = b2f(xdu.y),
                xdz = b2f(xdu.z), xdw = b2f(xdu.w);

    float a0 = 0.f, a1 = 0.f, a2 = 0.f, a3 = 0.f, sum = 0.f;
    const int b = rowptr[node];
    const int e = rowptr[node + 1];

    int i = b;
    for (; i + 1 < e; i += 2) {               // 2-wide for load overlap
        const int pk0 = pack[i];
        const int pk1 = pack[i + 1];
        const int s0 = pk0 & 0xFFFF, ty0 = pk0 >> 16;
        const int s1 = pk1 & 0xFFFF, ty1 = pk1 >> 16;
        const ushort4 u0 = *(const ushort4*)(xsrc + (size_t)s0 * HID + lane * 4);
        const float4  ev0 = *(const float4*)(eemb + (size_t)ty0 * HID + lane * 4);
        const ushort4 u1 = *(const ushort4*)(xsrc + (size_t)s1 * HID + lane * 4);
        const float4  ev1 = *(const float4*)(eemb + (size_t)ty1 * HID + lane * 4);
        const float x0x = b2f(u0.x), x0y = b2f(u0.y), x0z = b2f(u0.z), x0w = b2f(u0.w);
        const float x1x = b2f(u1.x), x1y = b2f(u1.y), x1z = b2f(u1.z), x1w = b2f(u1.w);
        float c, p0 = 0.f, p1 = 0.f;
        c = x0x + xdx + ev0.x; c = (c > 0.f) ? c : 0.2f * c; p0 = fmaf(c, av.x, p0);
        c = x0y + xdy + ev0.y; c = (c > 0.f) ? c : 0.2f * c; p0 = fmaf(c, av.y, p0);
        c = x0z + xdz + ev0.z; c = (c > 0.f) ? c : 0.2f * c; p0 = fmaf(c, av.z, p0);
        c = x0w + xdw + ev0.w; c = (c > 0.f) ? c : 0.2f * c; p0 = fmaf(c, av.w, p0);
        c = x1x + xdx + ev1.x; c = (c > 0.f) ? c : 0.2f * c; p1 = fmaf(c, av.x, p1);
        c = x1y + xdy + ev1.y; c = (c > 0.f) ? c : 0.2f * c; p1 = fmaf(c, av.y, p1);
        c = x1z + xdz + ev1.z; c = (c > 0.f) ? c : 0.2f * c; p1 = fmaf(c, av.z, p1);
        c = x1w + xdw + ev1.w; c = (c > 0.f) ? c : 0.2f * c; p1 = fmaf(c, av.w, p1);
        p0 += __shfl_xor(p0, 1); p1 += __shfl_xor(p1, 1);
        p0 += __shfl_xor(p0, 2); p1 += __shfl_xor(p1, 2);
        p0 += __shfl_xor(p0, 4); p1 += __shfl_xor(p1, 4);
        const float ex0 = expf(p0);
        const float ex1 = expf(p1);
        a0 = fmaf(ex0, x0x, a0); a1 = fmaf(ex0, x0y, a1);
        a2 = fmaf(ex0, x0z, a2); a3 = fmaf(ex0, x0w, a3);
        a0 = fmaf(ex1, x1x, a0); a1 = fmaf(ex1, x1y, a1);
        a2 = fmaf(ex1, x1z, a2); a3 = fmaf(ex1, x1w, a3);
        sum += ex0 + ex1;
    }
    if (i < e) {                              // tail
        const int pk0 = pack[i];
        const int s0 = pk0 & 0xFFFF, ty0 = pk0 >> 16;
        const ushort4 u0 = *(const ushort4*)(xsrc + (size_t)s0 * HID + lane * 4);
        const float4  ev0 = *(const float4*)(eemb + (size_t)ty0 * HID + lane * 4);
        const float x0x = b2f(u0.x), x0y = b2f(u0.y), x0z = b2f(u0.z), x0w = b2f(u0.w);
        float c, p0 = 0.f;
        c = x0x + xdx + ev0.x; c = (c > 0.f) ? c : 0.2f * c; p0 = fmaf(c, av.x, p0);
        c = x0y + xdy + ev0.y; c = (c > 0.f) ? c : 0.2f * c; p0 = fmaf(c, av.y, p0);
        c = x0z + xdz + ev0.z; c = (c > 0.f) ? c : 0.2f * c; p0 = fmaf(c, av.z, p0);
        c = x0w + xdw + ev0.w; c = (c > 0.f) ? c : 0.2f * c; p0 = fmaf(c, av.w, p0);
        p0 += __shfl_xor(p0, 1);
        p0 += __shfl_xor(p0, 2);
        p0 += __shfl_xor(p0, 4);
        const float ex0 = expf(p0);
        a0 = fmaf(ex0, x0x, a0); a1 = fmaf(ex0, x0y, a1);
        a2 = fmaf(ex0, x0z, a2); a3 = fmaf(ex0, x0w, a3);
        sum += ex0;
    }

    const float inv = 1.f / fmaxf(sum, 1e-12f);
    float4 o;
    o.x = a0 * inv; o.y = a1 * inv; o.z = a2 * inv; o.w = a3 * inv;
    *(float4*)(agg + (size_t)node * HID + lane * 4) = o;
}

// ---------------------------------------------------------------------------
// Finalize (GEMM-structured, fp32): 64-node tile in LDS, 256 threads.
// Single barrier after staging; LN via 32-lane shuffles.
// ---------------------------------------------------------------------------
__global__ __launch_bounds__(256) void finalize(
    const float* __restrict__ agg,
    const float* __restrict__ A,   const float* __restrict__ Wo,
    const float* __restrict__ bo,  const float* __restrict__ film,
    const float* __restrict__ nw_, const float* __restrict__ nb_,
    float* __restrict__ out)
{
    __shared__ float a_tile[64][HID];
    const int t  = threadIdx.x;
    const int nb = blockIdx.x * 64;

    #pragma unroll
    for (int i = 0; i < 8; ++i) {
        int f  = t + 256 * i;        // float4 index within tile
        int m  = f >> 5;
        int k4 = f & 31;
        int node = nb + m;
        float4 v;
        if (node < N_NODES) v = *(const float4*)(agg + (size_t)node * HID + k4 * 4);
        else { v.x = v.y = v.z = v.w = 0.f; }
        *(float4*)&a_tile[m][k4 * 4] = v;
    }
    __syncthreads();

    const int cg = t & 31;
    const int rg = t >> 5;            // 8 row-groups of 8 nodes
    const int cc = cg * 4;
    const int m0 = rg * 8;

    float acc[8][4];
    #pragma unroll
    for (int m = 0; m < 8; ++m)
        #pragma unroll
        for (int j = 0; j < 4; ++j) acc[m][j] = 0.f;

    for (int kc = 0; kc < 32; ++kc) {
        const int k0 = kc * 4;
        const float4 w0 = *(const float4*)(Wo + (size_t)(k0 + 0) * HID + cc);
        const float4 w1 = *(const float4*)(Wo + (size_t)(k0 + 1) * HID + cc);
        const float4 w2 = *(const float4*)(Wo + (size_t)(k0 + 2) * HID + cc);
        const float4 w3 = *(const float4*)(Wo + (size_t)(k0 + 3) * HID + cc);
        #pragma unroll
        for (int m = 0; m < 8; ++m) {
            const float4 av = *(const float4*)&a_tile[m0 + m][k0];
            acc[m][0] = fmaf(av.x, w0.x, acc[m][0]);
            acc[m][1] = fmaf(av.x, w0.y, acc[m][1]);
            acc[m][2] = fmaf(av.x, w0.z, acc[m][2]);
            acc[m][3] = fmaf(av.x, w0.w, acc[m][3]);
            acc[m][0] = fmaf(av.y, w1.x, acc[m][0]);
            acc[m][1] = fmaf(av.y, w1.y, acc[m][1]);
            acc[m][2] = fmaf(av.y, w1.z, acc[m][2]);
            acc[m][3] = fmaf(av.y, w1.w, acc[m][3]);
            acc[m][0] = fmaf(av.z, w2.x, acc[m][0]);
            acc[m][1] = fmaf(av.z, w2.y, acc[m][1]);
            acc[m][2] = fmaf(av.z, w2.z, acc[m][2]);
            acc[m][3] = fmaf(av.z, w2.w, acc[m][3]);
            acc[m][0] = fmaf(av.w, w3.x, acc[m][0]);
            acc[m][1] = fmaf(av.w, w3.y, acc[m][1]);
            acc[m][2] = fmaf(av.w, w3.z, acc[m][2]);
            acc[m][3] = fmaf(av.w, w3.w, acc[m][3]);
        }
    }

    const float4 bv  = *(const float4*)(bo   + cc);
    const float4 gfv = *(const float4*)(film + cc);
    const float4 btv = *(const float4*)(film + HID + cc);
    const float4 nwv = *(const float4*)(nw_  + cc);
    const float4 nbv = *(const float4*)(nb_  + cc);

    #pragma unroll
    for (int m = 0; m < 8; ++m) {
        const int node = nb + m0 + m;
        float4 y;
        float4 r;
        if (node < N_NODES) r = *(const float4*)(A + (size_t)node * HID + cc);
        else { r.x = r.y = r.z = r.w = 0.f; }
        y.x = fmaf(acc[m][0] + bv.x, gfv.x, btv.x) + r.x;
        y.y = fmaf(acc[m][1] + bv.y, gfv.y, btv.y) + r.y;
        y.z = fmaf(acc[m][2] + bv.z, gfv.z, btv.z) + r.z;
        y.w = fmaf(acc[m][3] + bv.w, gfv.w, btv.w) + r.w;

        float s1 = y.x + y.y + y.z + y.w;
        float s2 = y.x * y.x + y.y * y.y + y.z * y.z + y.w * y.w;
        #pragma unroll
        for (int off = 1; off < 32; off <<= 1) {
            s1 += __shfl_xor(s1, off);
            s2 += __shfl_xor(s2, off);
        }
        const float mu   = s1 * (1.f / 128.f);
        const float var  = s2 * (1.f / 128.f) - mu * mu;
        const float rsig = rsqrtf(var + 1e-5f);
        if (node < N_NODES) {
            float4 o;
            o.x = (y.x - mu) * rsig * nwv.x + nbv.x;
            o.y = (y.y - mu) * rsig * nwv.y + nbv.y;
            o.z = (y.z - mu) * rsig * nwv.z + nbv.z;
            o.w = (y.w - mu) * rsig * nwv.w + nbv.w;
            *(float4*)(out + (size_t)node * HID + cc) = o;
        }
    }
}

// ---------------------------------------------------------------------------
extern "C" void kernel_launch(void* const* d_in, const int* in_sizes, int n_in,
                              void* d_out, int out_size, void* d_ws, size_t ws_size,
                              hipStream_t stream)
{
    const float* node_emb = (const float*)d_in[0];
    const int*   edge_idx = (const int*)  d_in[1];
    const int*   edge_ty  = (const int*)  d_in[2];
    const float* task     = (const float*)d_in[3];
    const float* W_src    = (const float*)d_in[4];
    const float* b_src    = (const float*)d_in[5];
    const float* W_dst    = (const float*)d_in[6];
    const float* b_dst    = (const float*)d_in[7];
    const float* edge_emb = (const float*)d_in[8];
    const float* att      = (const float*)d_in[9];
    const float* W_out    = (const float*)d_in[10];
    const float* b_out    = (const float*)d_in[11];
    const float* norm_w   = (const float*)d_in[12];
    const float* norm_b   = (const float*)d_in[13];
    const float* W_film   = (const float*)d_in[14];
    const float* b_film   = (const float*)d_in[15];
    float* out = (float*)d_out;

    char* ws = (char*)d_ws;
    float* agg      = (float*)ws;                            ws += (size_t)N_NODES * HID * 4;
    float* film     = (float*)ws;                            ws += 256 * 4;
    int*   deg      = (int*)ws;                              ws += (size_t)N_NODES * 4;
    int*   rowptr   = (int*)ws;                              ws += (size_t)(N_NODES + 1) * 4;
    int*   cursor   = (int*)ws;                              ws += (size_t)N_NODES * 4;
    int*   blocksum = (int*)ws;                              ws += 256 * 4;
    int*   blockoff = (int*)ws;                              ws += 256 * 4;
    int*   pack     = (int*)ws;                              ws += (size_t)E_EDGES * 4;
    unsigned short* x_src = (unsigned short*)ws;             ws += (size_t)N_NODES * HID * 2;
    unsigned short* x_dst = (unsigned short*)ws;             ws += (size_t)N_NODES * HID * 2;
    short* wb1      = (short*)ws;                            ws += (size_t)256 * HID * 2;

    hipMemsetAsync(deg, 0, (size_t)N_NODES * sizeof(int), stream);

    film_kernel<<<1, 256, 0, stream>>>(task, W_film, b_film, film);
    hist_kernel<<<(E_EDGES + 255) / 256, 256, 0, stream>>>(edge_idx, deg);
    prep_weights<<<(256 * HID) / 256, 256, 0, stream>>>(W_src, W_dst, wb1);
    gemm_mfma<<<(N_NODES + 63) / 64, 256, 0, stream>>>(
        node_emb, wb1, b_src, b_dst, x_src, x_dst);
    reduce_blocks<<<SCAN_BLOCKS, 256, 0, stream>>>(deg, blocksum);
    scan_blocksums<<<1, 256, 0, stream>>>(blocksum, blockoff, rowptr);
    scan_within<<<SCAN_BLOCKS, 256, 0, stream>>>(deg, blockoff, rowptr, cursor);
    scatter_kernel<<<(E_EDGES + 255) / 256, 256, 0, stream>>>(
        edge_idx, edge_ty, cursor, pack);
    gather_agg<<<(N_NODES + 7) / 8, 256, 0, stream>>>(
        rowptr, pack, x_src, x_dst, edge_emb, att, agg);
    finalize<<<(N_NODES + 63) / 64, 256, 0, stream>>>(
        agg, node_emb, W_out, b_out, film, norm_w, norm_b, out);
}

// Round 7
// 255.816 us; speedup vs baseline: 1.1605x; 1.1338x over previous
//
#include <hip/hip_runtime.h>
#include <hip/hip_bf16.h>

#define N_NODES 50000
#define E_EDGES 500000
#define HID 128
#define NHEAD 4
#define HDIM 32
#define SCAN_BLOCKS ((N_NODES + 255) / 256)   // 196

typedef __attribute__((ext_vector_type(8))) short bf16x8;          // MFMA operand
typedef __attribute__((ext_vector_type(8))) unsigned short u16x8;  // 16B copy
typedef __attribute__((ext_vector_type(4))) float f32x4;

static __device__ __forceinline__ float b2f(unsigned short u) {
    return __uint_as_float((unsigned int)u << 16);
}
static __device__ __forceinline__ unsigned short f2b(float f) {
    unsigned int u = __float_as_uint(f);
    u += 0x7FFFu + ((u >> 16) & 1u);          // round-to-nearest-even
    return (unsigned short)(u >> 16);
}

// ---------------------------------------------------------------------------
// FiLM: film[j] = task @ W_film[:,j] + b_film[j]; store gamma-factor and beta
// ---------------------------------------------------------------------------
__global__ __launch_bounds__(256) void film_kernel(
    const float* __restrict__ task, const float* __restrict__ Wf,
    const float* __restrict__ bf, float* __restrict__ film)
{
    __shared__ float tsk[HID];
    const int t = threadIdx.x;
    if (t < HID) tsk[t] = task[t];
    __syncthreads();
    float acc = bf[t];
    #pragma unroll 8
    for (int k = 0; k < HID; ++k)
        acc = fmaf(tsk[k], Wf[k * 256 + t], acc);
    if (t < HID) film[t] = 1.f + 0.5f * tanhf(acc);   // gamma factor
    else         film[t] = acc;                        // beta
}

// ---------------------------------------------------------------------------
// Weight prep: B1 = bf16 [W_src^T ; W_dst^T], stored PRE-XOR-SWIZZLED
// (byte ^= (n&7)<<4) so gemm_mfma can linear-copy it into LDS and read
// fragments conflict-free with the same swizzle.
// ---------------------------------------------------------------------------
__global__ __launch_bounds__(256) void prep_weights(
    const float* __restrict__ Ws, const float* __restrict__ Wd,
    unsigned short* __restrict__ B1)
{
    const int id = blockIdx.x * 256 + threadIdx.x;   // 256*128 total
    const int n = id >> 7;
    const int k = id & 127;
    const float v = (n < HID) ? Ws[(size_t)k * HID + n]
                              : Wd[(size_t)k * HID + (n - HID)];
    size_t byte = ((size_t)n * HID + k) * 2;
    byte ^= (size_t)((n & 7) << 4);
    *(unsigned short*)((char*)B1 + byte) = f2b(v);
}

// ---------------------------------------------------------------------------
// MFMA input GEMM: [64 nodes] x [256 cols], K=128.
// B staged in LDS (64 KB, pre-swizzled); wave w owns col quadrant w*64..+63.
// Per wave: 4x4 fragment grid, 4 k-steps -> 64 MFMA, 8 ds_read_b128/k-step.
// Epilogue via c_lds overlay -> coalesced 16B bf16 stores.
// ---------------------------------------------------------------------------
__global__ __launch_bounds__(256) void gemm_mfma(
    const float* __restrict__ A, const unsigned short* __restrict__ B1,
    const float* __restrict__ bs, const float* __restrict__ bd,
    unsigned short* __restrict__ xs, unsigned short* __restrict__ xd)
{
    __shared__ unsigned short a_lds[64 * HID];    // 16 KB, swizzled
    __shared__ unsigned short b_lds[256 * HID];   // 64 KB, swizzled (linear copy)
    const int t  = threadIdx.x;
    const int nb = blockIdx.x * 64;

    // ---- stage A: fp32 -> bf16, XOR swizzle ----
    #pragma unroll
    for (int i = 0; i < 8; ++i) {
        const int f   = t + 256 * i;
        const int row = f >> 5;
        const int k4  = f & 31;
        const int node = nb + row;
        float4 v;
        if (node < N_NODES) v = *(const float4*)(A + (size_t)node * HID + k4 * 4);
        else { v.x = v.y = v.z = v.w = 0.f; }
        ushort4 h;
        h.x = f2b(v.x); h.y = f2b(v.y); h.z = f2b(v.z); h.w = f2b(v.w);
        int byte = row * 256 + k4 * 8;
        byte ^= (row & 7) << 4;
        *(ushort4*)((char*)a_lds + byte) = h;
    }
    // ---- stage B: linear 16B copy (swizzle pre-applied in memory) ----
    #pragma unroll
    for (int i = 0; i < 16; ++i) {
        const int off = (t + 256 * i) * 8;        // ushort index
        const u16x8 v = *(const u16x8*)(B1 + off);
        *(u16x8*)(b_lds + off) = v;
    }
    __syncthreads();

    const int w   = t >> 6;
    const int l   = t & 63;
    const int l15 = l & 15;
    const int kg  = l >> 4;

    f32x4 acc[4][4];
    #pragma unroll
    for (int mf = 0; mf < 4; ++mf)
        #pragma unroll
        for (int nf = 0; nf < 4; ++nf) acc[mf][nf] = (f32x4){0.f, 0.f, 0.f, 0.f};

    #pragma unroll
    for (int ks = 0; ks < 4; ++ks) {
        bf16x8 af[4], bfg[4];
        #pragma unroll
        for (int mf = 0; mf < 4; ++mf) {
            const int r = mf * 16 + l15;
            int byte = r * 256 + ks * 64 + kg * 16;
            byte ^= (r & 7) << 4;
            af[mf] = *(const bf16x8*)((const char*)a_lds + byte);
        }
        #pragma unroll
        for (int nf = 0; nf < 4; ++nf) {
            const int rb = w * 64 + nf * 16 + l15;
            int byte = rb * 256 + ks * 64 + kg * 16;
            byte ^= (rb & 7) << 4;
            bfg[nf] = *(const bf16x8*)((const char*)b_lds + byte);
        }
        #pragma unroll
        for (int mf = 0; mf < 4; ++mf)
            #pragma unroll
            for (int nf = 0; nf < 4; ++nf)
                acc[mf][nf] = __builtin_amdgcn_mfma_f32_16x16x32_bf16(
                    af[mf], bfg[nf], acc[mf][nf], 0, 0, 0);
    }

    // ---- bias (per nf, col = w*64 + nf*16 + l15; uniform src/dst per nf) ----
    float bias[4];
    #pragma unroll
    for (int nf = 0; nf < 4; ++nf) {
        const int col = w * 64 + nf * 16 + l15;
        bias[nf] = (col < HID) ? bs[col] : bd[col - HID];
    }

    __syncthreads();                              // b_lds reads complete
    unsigned short* c_lds = b_lds;                // overlay, stride 264 shorts

    #pragma unroll
    for (int mf = 0; mf < 4; ++mf)
        #pragma unroll
        for (int nf = 0; nf < 4; ++nf) {
            const int col = w * 64 + nf * 16 + l15;
            #pragma unroll
            for (int j = 0; j < 4; ++j) {
                const int row = mf * 16 + kg * 4 + j;   // C/D: row=(lane>>4)*4+reg
                c_lds[row * 264 + col] = f2b(acc[mf][nf][j] + bias[nf]);
            }
        }
    __syncthreads();

    // ---- coalesced stores: 8 passes x (2 rows x 32 chunks per wave) ----
    #pragma unroll
    for (int p = 0; p < 8; ++p) {
        const int row   = p * 8 + (t >> 5);
        const int chunk = t & 31;
        const int node  = nb + row;
        if (node < N_NODES) {
            const u16x8 v = *(const u16x8*)(c_lds + row * 264 + chunk * 8);
            if (chunk < 16)
                *(u16x8*)(xs + (size_t)node * HID + chunk * 8) = v;
            else
                *(u16x8*)(xd + (size_t)node * HID + (chunk - 16) * 8) = v;
        }
    }
}

// ---------------------------------------------------------------------------
// CSR build, step 1: in-degree histogram over dst
// ---------------------------------------------------------------------------
__global__ __launch_bounds__(256) void hist_kernel(
    const int* __restrict__ ei, int* __restrict__ deg)
{
    const int e = blockIdx.x * 256 + threadIdx.x;
    if (e < E_EDGES) atomicAdd(&deg[ei[E_EDGES + e]], 1);
}

// ---------------------------------------------------------------------------
// Two-level scan, step A: per-block (256-wide) reduction of deg
// ---------------------------------------------------------------------------
__global__ __launch_bounds__(256) void reduce_blocks(
    const int* __restrict__ deg, int* __restrict__ blocksum)
{
    __shared__ int ws_[4];
    const int t = threadIdx.x;
    const int i = blockIdx.x * 256 + t;
    int v = (i < N_NODES) ? deg[i] : 0;
    #pragma unroll
    for (int off = 32; off; off >>= 1) v += __shfl_down(v, off);
    if ((t & 63) == 0) ws_[t >> 6] = v;
    __syncthreads();
    if (t == 0) blocksum[blockIdx.x] = ws_[0] + ws_[1] + ws_[2] + ws_[3];
}

// ---------------------------------------------------------------------------
// Two-level scan, step B: scan the 196 block sums -> exclusive block offsets
// ---------------------------------------------------------------------------
__global__ __launch_bounds__(256) void scan_blocksums(
    const int* __restrict__ blocksum, int* __restrict__ blockoff,
    int* __restrict__ rowptr)
{
    __shared__ int wtot[4];
    const int t    = threadIdx.x;
    const int lane = t & 63;
    const int w    = t >> 6;
    int v = (t < SCAN_BLOCKS) ? blocksum[t] : 0;
    const int own = v;
    #pragma unroll
    for (int off = 1; off < 64; off <<= 1) {
        const int u = __shfl_up(v, off);
        if (lane >= off) v += u;
    }
    if (lane == 63) wtot[w] = v;
    __syncthreads();
    int woff = 0;
    #pragma unroll
    for (int k = 0; k < 4; ++k) if (k < w) woff += wtot[k];
    if (t < SCAN_BLOCKS) blockoff[t] = woff + v - own;   // exclusive
    if (t == 0) rowptr[N_NODES] = E_EDGES;
}

// ---------------------------------------------------------------------------
// Two-level scan, step C: per-block exclusive scan + offset -> rowptr, cursor
// ---------------------------------------------------------------------------
__global__ __launch_bounds__(256) void scan_within(
    const int* __restrict__ deg, const int* __restrict__ blockoff,
    int* __restrict__ rowptr, int* __restrict__ cursor)
{
    __shared__ int wtot[4];
    const int t    = threadIdx.x;
    const int lane = t & 63;
    const int w    = t >> 6;
    const int i    = blockIdx.x * 256 + t;
    int v = (i < N_NODES) ? deg[i] : 0;
    const int own = v;
    #pragma unroll
    for (int off = 1; off < 64; off <<= 1) {
        const int u = __shfl_up(v, off);
        if (lane >= off) v += u;
    }
    if (lane == 63) wtot[w] = v;
    __syncthreads();
    int woff = blockoff[blockIdx.x];
    #pragma unroll
    for (int k = 0; k < 4; ++k) if (k < w) woff += wtot[k];
    if (i < N_NODES) {
        const int ex = woff + v - own;
        rowptr[i] = ex;
        cursor[i] = ex;
    }
}

// ---------------------------------------------------------------------------
// CSR build, step 3: scatter packed (src | etype<<16) records into dst bins
// ---------------------------------------------------------------------------
__global__ __launch_bounds__(256) void scatter_kernel(
    const int* __restrict__ ei, const int* __restrict__ et,
    int* __restrict__ cursor, int* __restrict__ pack)
{
    const int e = blockIdx.x * 256 + threadIdx.x;
    if (e < E_EDGES) {
        const int d = ei[E_EDGES + e];
        const int pos = atomicAdd(&cursor[d], 1);
        pack[pos] = ei[e] | (et[e] << 16);    // src < 65536, etype < 8
    }
}

// ---------------------------------------------------------------------------
// Gather-aggregate (bf16 x inputs): one 32-lane group per dst node.
// ---------------------------------------------------------------------------
__global__ __launch_bounds__(256) void gather_agg(
    const int* __restrict__ rowptr, const int* __restrict__ pack,
    const unsigned short* __restrict__ xsrc,
    const unsigned short* __restrict__ xdst,
    const float* __restrict__ eemb, const float* __restrict__ att,
    float* __restrict__ agg)
{
    const int lane = threadIdx.x & 31;
    const int grp  = threadIdx.x >> 5;
    const int node = blockIdx.x * 8 + grp;
    if (node >= N_NODES) return;

    const float4 av = *(const float4*)(att + lane * 4);
    const ushort4 xdu = *(const ushort4*)(xdst + (size_t)node * HID + lane * 4);
    const float xdx = b2f(xdu.x), xdy = b2f(xdu.y),
                xdz = b2f(xdu.z), xdw = b2f(xdu.w);

    float a0 = 0.f, a1 = 0.f, a2 = 0.f, a3 = 0.f, sum = 0.f;
    const int b = rowptr[node];
    const int e = rowptr[node + 1];

    int i = b;
    for (; i + 1 < e; i += 2) {               // 2-wide for load overlap
        const int pk0 = pack[i];
        const int pk1 = pack[i + 1];
        const int s0 = pk0 & 0xFFFF, ty0 = pk0 >> 16;
        const int s1 = pk1 & 0xFFFF, ty1 = pk1 >> 16;
        const ushort4 u0 = *(const ushort4*)(xsrc + (size_t)s0 * HID + lane * 4);
        const float4  ev0 = *(const float4*)(eemb + (size_t)ty0 * HID + lane * 4);
        const ushort4 u1 = *(const ushort4*)(xsrc + (size_t)s1 * HID + lane * 4);
        const float4  ev1 = *(const float4*)(eemb + (size_t)ty1 * HID + lane * 4);
        const float x0x = b2f(u0.x), x0y = b2f(u0.y), x0z = b2f(u0.z), x0w = b2f(u0.w);
        const float x1x = b2f(u1.x), x1y = b2f(u1.y), x1z = b2f(u1.z), x1w = b2f(u1.w);
        float c, p0 = 0.f, p1 = 0.f;
        c = x0x + xdx + ev0.x; c = (c > 0.f) ? c : 0.2f * c; p0 = fmaf(c, av.x, p0);
        c = x0y + xdy + ev0.y; c = (c > 0.f) ? c : 0.2f * c; p0 = fmaf(c, av.y, p0);
        c = x0z + xdz + ev0.z; c = (c > 0.f) ? c : 0.2f * c; p0 = fmaf(c, av.z, p0);
        c = x0w + xdw + ev0.w; c = (c > 0.f) ? c : 0.2f * c; p0 = fmaf(c, av.w, p0);
        c = x1x + xdx + ev1.x; c = (c > 0.f) ? c : 0.2f * c; p1 = fmaf(c, av.x, p1);
        c = x1y + xdy + ev1.y; c = (c > 0.f) ? c : 0.2f * c; p1 = fmaf(c, av.y, p1);
        c = x1z + xdz + ev1.z; c = (c > 0.f) ? c : 0.2f * c; p1 = fmaf(c, av.z, p1);
        c = x1w + xdw + ev1.w; c = (c > 0.f) ? c : 0.2f * c; p1 = fmaf(c, av.w, p1);
        p0 += __shfl_xor(p0, 1); p1 += __shfl_xor(p1, 1);
        p0 += __shfl_xor(p0, 2); p1 += __shfl_xor(p1, 2);
        p0 += __shfl_xor(p0, 4); p1 += __shfl_xor(p1, 4);
        const float ex0 = expf(p0);
        const float ex1 = expf(p1);
        a0 = fmaf(ex0, x0x, a0); a1 = fmaf(ex0, x0y, a1);
        a2 = fmaf(ex0, x0z, a2); a3 = fmaf(ex0, x0w, a3);
        a0 = fmaf(ex1, x1x, a0); a1 = fmaf(ex1, x1y, a1);
        a2 = fmaf(ex1, x1z, a2); a3 = fmaf(ex1, x1w, a3);
        sum += ex0 + ex1;
    }
    if (i < e) {                              // tail
        const int pk0 = pack[i];
        const int s0 = pk0 & 0xFFFF, ty0 = pk0 >> 16;
        const ushort4 u0 = *(const ushort4*)(xsrc + (size_t)s0 * HID + lane * 4);
        const float4  ev0 = *(const float4*)(eemb + (size_t)ty0 * HID + lane * 4);
        const float x0x = b2f(u0.x), x0y = b2f(u0.y), x0z = b2f(u0.z), x0w = b2f(u0.w);
        float c, p0 = 0.f;
        c = x0x + xdx + ev0.x; c = (c > 0.f) ? c : 0.2f * c; p0 = fmaf(c, av.x, p0);
        c = x0y + xdy + ev0.y; c = (c > 0.f) ? c : 0.2f * c; p0 = fmaf(c, av.y, p0);
        c = x0z + xdz + ev0.z; c = (c > 0.f) ? c : 0.2f * c; p0 = fmaf(c, av.z, p0);
        c = x0w + xdw + ev0.w; c = (c > 0.f) ? c : 0.2f * c; p0 = fmaf(c, av.w, p0);
        p0 += __shfl_xor(p0, 1);
        p0 += __shfl_xor(p0, 2);
        p0 += __shfl_xor(p0, 4);
        const float ex0 = expf(p0);
        a0 = fmaf(ex0, x0x, a0); a1 = fmaf(ex0, x0y, a1);
        a2 = fmaf(ex0, x0z, a2); a3 = fmaf(ex0, x0w, a3);
        sum += ex0;
    }

    const float inv = 1.f / fmaxf(sum, 1e-12f);
    float4 o;
    o.x = a0 * inv; o.y = a1 * inv; o.z = a2 * inv; o.w = a3 * inv;
    *(float4*)(agg + (size_t)node * HID + lane * 4) = o;
}

// ---------------------------------------------------------------------------
// Finalize (GEMM-structured, fp32): 64-node tile in LDS, 256 threads.
// Single barrier after staging; LN via 32-lane shuffles.
// ---------------------------------------------------------------------------
__global__ __launch_bounds__(256) void finalize(
    const float* __restrict__ agg,
    const float* __restrict__ A,   const float* __restrict__ Wo,
    const float* __restrict__ bo,  const float* __restrict__ film,
    const float* __restrict__ nw_, const float* __restrict__ nb_,
    float* __restrict__ out)
{
    __shared__ float a_tile[64][HID];
    const int t  = threadIdx.x;
    const int nb = blockIdx.x * 64;

    #pragma unroll
    for (int i = 0; i < 8; ++i) {
        int f  = t + 256 * i;        // float4 index within tile
        int m  = f >> 5;
        int k4 = f & 31;
        int node = nb + m;
        float4 v;
        if (node < N_NODES) v = *(const float4*)(agg + (size_t)node * HID + k4 * 4);
        else { v.x = v.y = v.z = v.w = 0.f; }
        *(float4*)&a_tile[m][k4 * 4] = v;
    }
    __syncthreads();

    const int cg = t & 31;
    const int rg = t >> 5;            // 8 row-groups of 8 nodes
    const int cc = cg * 4;
    const int m0 = rg * 8;

    float acc[8][4];
    #pragma unroll
    for (int m = 0; m < 8; ++m)
        #pragma unroll
        for (int j = 0; j < 4; ++j) acc[m][j] = 0.f;

    for (int kc = 0; kc < 32; ++kc) {
        const int k0 = kc * 4;
        const float4 w0 = *(const float4*)(Wo + (size_t)(k0 + 0) * HID + cc);
        const float4 w1 = *(const float4*)(Wo + (size_t)(k0 + 1) * HID + cc);
        const float4 w2 = *(const float4*)(Wo + (size_t)(k0 + 2) * HID + cc);
        const float4 w3 = *(const float4*)(Wo + (size_t)(k0 + 3) * HID + cc);
        #pragma unroll
        for (int m = 0; m < 8; ++m) {
            const float4 av = *(const float4*)&a_tile[m0 + m][k0];
            acc[m][0] = fmaf(av.x, w0.x, acc[m][0]);
            acc[m][1] = fmaf(av.x, w0.y, acc[m][1]);
            acc[m][2] = fmaf(av.x, w0.z, acc[m][2]);
            acc[m][3] = fmaf(av.x, w0.w, acc[m][3]);
            acc[m][0] = fmaf(av.y, w1.x, acc[m][0]);
            acc[m][1] = fmaf(av.y, w1.y, acc[m][1]);
            acc[m][2] = fmaf(av.y, w1.z, acc[m][2]);
            acc[m][3] = fmaf(av.y, w1.w, acc[m][3]);
            acc[m][0] = fmaf(av.z, w2.x, acc[m][0]);
            acc[m][1] = fmaf(av.z, w2.y, acc[m][1]);
            acc[m][2] = fmaf(av.z, w2.z, acc[m][2]);
            acc[m][3] = fmaf(av.z, w2.w, acc[m][3]);
            acc[m][0] = fmaf(av.w, w3.x, acc[m][0]);
            acc[m][1] = fmaf(av.w, w3.y, acc[m][1]);
            acc[m][2] = fmaf(av.w, w3.z, acc[m][2]);
            acc[m][3] = fmaf(av.w, w3.w, acc[m][3]);
        }
    }

    const float4 bv  = *(const float4*)(bo   + cc);
    const float4 gfv = *(const float4*)(film + cc);
    const float4 btv = *(const float4*)(film + HID + cc);
    const float4 nwv = *(const float4*)(nw_  + cc);
    const float4 nbv = *(const float4*)(nb_  + cc);

    #pragma unroll
    for (int m = 0; m < 8; ++m) {
        const int node = nb + m0 + m;
        float4 y;
        float4 r;
        if (node < N_NODES) r = *(const float4*)(A + (size_t)node * HID + cc);
        else { r.x = r.y = r.z = r.w = 0.f; }
        y.x = fmaf(acc[m][0] + bv.x, gfv.x, btv.x) + r.x;
        y.y = fmaf(acc[m][1] + bv.y, gfv.y, btv.y) + r.y;
        y.z = fmaf(acc[m][2] + bv.z, gfv.z, btv.z) + r.z;
        y.w = fmaf(acc[m][3] + bv.w, gfv.w, btv.w) + r.w;

        float s1 = y.x + y.y + y.z + y.w;
        float s2 = y.x * y.x + y.y * y.y + y.z * y.z + y.w * y.w;
        #pragma unroll
        for (int off = 1; off < 32; off <<= 1) {
            s1 += __shfl_xor(s1, off);
            s2 += __shfl_xor(s2, off);
        }
        const float mu   = s1 * (1.f / 128.f);
        const float var  = s2 * (1.f / 128.f) - mu * mu;
        const float rsig = rsqrtf(var + 1e-5f);
        if (node < N_NODES) {
            float4 o;
            o.x = (y.x - mu) * rsig * nwv.x + nbv.x;
            o.y = (y.y - mu) * rsig * nwv.y + nbv.y;
            o.z = (y.z - mu) * rsig * nwv.z + nbv.z;
            o.w = (y.w - mu) * rsig * nwv.w + nbv.w;
            *(float4*)(out + (size_t)node * HID + cc) = o;
        }
    }
}

// ---------------------------------------------------------------------------
extern "C" void kernel_launch(void* const* d_in, const int* in_sizes, int n_in,
                              void* d_out, int out_size, void* d_ws, size_t ws_size,
                              hipStream_t stream)
{
    const float* node_emb = (const float*)d_in[0];
    const int*   edge_idx = (const int*)  d_in[1];
    const int*   edge_ty  = (const int*)  d_in[2];
    const float* task     = (const float*)d_in[3];
    const float* W_src    = (const float*)d_in[4];
    const float* b_src    = (const float*)d_in[5];
    const float* W_dst    = (const float*)d_in[6];
    const float* b_dst    = (const float*)d_in[7];
    const float* edge_emb = (const float*)d_in[8];
    const float* att      = (const float*)d_in[9];
    const float* W_out    = (const float*)d_in[10];
    const float* b_out    = (const float*)d_in[11];
    const float* norm_w   = (const float*)d_in[12];
    const float* norm_b   = (const float*)d_in[13];
    const float* W_film   = (const float*)d_in[14];
    const float* b_film   = (const float*)d_in[15];
    float* out = (float*)d_out;

    // NOTE: every segment size is a multiple of 16 B (rowptr padded) so the
    // 16 B vector loads/stores on x_src/x_dst/B1 are aligned.
    char* ws = (char*)d_ws;
    float* agg      = (float*)ws;                            ws += (size_t)N_NODES * HID * 4;
    float* film     = (float*)ws;                            ws += 256 * 4;
    int*   deg      = (int*)ws;                              ws += (size_t)N_NODES * 4;
    int*   rowptr   = (int*)ws;                              ws += (size_t)(N_NODES + 4) * 4;
    int*   cursor   = (int*)ws;                              ws += (size_t)N_NODES * 4;
    int*   blocksum = (int*)ws;                              ws += 256 * 4;
    int*   blockoff = (int*)ws;                              ws += 256 * 4;
    int*   pack     = (int*)ws;                              ws += (size_t)E_EDGES * 4;
    unsigned short* x_src = (unsigned short*)ws;             ws += (size_t)N_NODES * HID * 2;
    unsigned short* x_dst = (unsigned short*)ws;             ws += (size_t)N_NODES * HID * 2;
    unsigned short* wb1   = (unsigned short*)ws;             ws += (size_t)256 * HID * 2;

    hipMemsetAsync(deg, 0, (size_t)N_NODES * sizeof(int), stream);

    film_kernel<<<1, 256, 0, stream>>>(task, W_film, b_film, film);
    hist_kernel<<<(E_EDGES + 255) / 256, 256, 0, stream>>>(edge_idx, deg);
    prep_weights<<<(256 * HID) / 256, 256, 0, stream>>>(W_src, W_dst, wb1);
    gemm_mfma<<<(N_NODES + 63) / 64, 256, 0, stream>>>(
        node_emb, wb1, b_src, b_dst, x_src, x_dst);
    reduce_blocks<<<SCAN_BLOCKS, 256, 0, stream>>>(deg, blocksum);
    scan_blocksums<<<1, 256, 0, stream>>>(blocksum, blockoff, rowptr);
    scan_within<<<SCAN_BLOCKS, 256, 0, stream>>>(deg, blockoff, rowptr, cursor);
    scatter_kernel<<<(E_EDGES + 255) / 256, 256, 0, stream>>>(
        edge_idx, edge_ty, cursor, pack);
    gather_agg<<<(N_NODES + 7) / 8, 256, 0, stream>>>(
        rowptr, pack, x_src, x_dst, edge_emb, att, agg);
    finalize<<<(N_NODES + 63) / 64, 256, 0, stream>>>(
        agg, node_emb, W_out, b_out, film, norm_w, norm_b, out);
}